// Round 2
// baseline (6795.467 us; speedup 1.0000x reference)
//
#include <hip/hip_runtime.h>

#define DI __device__ __forceinline__

typedef __attribute__((ext_vector_type(8))) short short8v;
typedef __attribute__((ext_vector_type(4))) float f32x4;

// ---------- small helpers ----------
DI short f2bf(float f) {
  unsigned u = __float_as_uint(f);
  u += 0x7fffu + ((u >> 16) & 1u);  // RNE
  return (short)(u >> 16);
}

DI float waveRed(float v) {
#pragma unroll
  for (int m = 32; m; m >>= 1) v += __shfl_xor(v, m, 64);
  return v;
}

DI float tanh_fast(float x) {
  float ax = fabsf(x);
  float e = __expf(2.f * ax);
  float t = 1.f - 2.f / (e + 1.f);
  return copysignf(t, x);
}

DI void gl16(const void* g, void* l) {
  // 16B-wide async global->LDS; LDS dest = wave-uniform base + lane*16
  __builtin_amdgcn_global_load_lds((const __attribute__((address_space(1))) void*)g,
                                   (__attribute__((address_space(3))) void*)l, 16, 0, 0);
}

// ---------- GEMM: C[M,N] = A[M,K](bf16) * B (BT[N,K] bf16) + bias ----------
// 128x128 tile, BK=32, 256 threads (4 waves as 2x2), mfma 16x16x32 bf16.
template <int BF16OUT>
__global__ __launch_bounds__(256) void gemm_k(const short* __restrict__ A,
                                              const short* __restrict__ BT,
                                              const float* __restrict__ bias,
                                              void* __restrict__ C, int M, int N, int K) {
  __shared__ short sA[2][8][512];  // [dbuf][m-subtile][lane*8] fragment-linear
  __shared__ short sB[2][8][512];
  const int tid = threadIdx.x, lane = tid & 63, wid = tid >> 6;
  const int tm = blockIdx.x << 7, tn = blockIdx.y << 7;
  const int wm = wid >> 1, wn = wid & 1;
  const int r15 = lane & 15, kq = (lane >> 4) << 3;
  const int KT = K >> 5;

  f32x4 acc[4][4];
#pragma unroll
  for (int i = 0; i < 4; i++)
#pragma unroll
    for (int j = 0; j < 4; j++) acc[i][j] = f32x4{0.f, 0.f, 0.f, 0.f};

  auto stage = [&](int kt, int buf) {
    const int k0 = kt << 5;
#pragma unroll
    for (int i = 0; i < 2; i++) {
      const int st = (wid << 1) | i;
      gl16(A + (size_t)(tm + (st << 4) + r15) * K + k0 + kq, &sA[buf][st][0]);
      gl16(BT + (size_t)(tn + (st << 4) + r15) * K + k0 + kq, &sB[buf][st][0]);
    }
  };

  stage(0, 0);
  __syncthreads();
  int cur = 0;
  for (int kt = 0; kt < KT; ++kt) {
    if (kt + 1 < KT) stage(kt + 1, cur ^ 1);
    short8v a[4], b[4];
#pragma unroll
    for (int i = 0; i < 4; i++) a[i] = *(const short8v*)&sA[cur][(wm << 2) | i][lane << 3];
#pragma unroll
    for (int j = 0; j < 4; j++) b[j] = *(const short8v*)&sB[cur][(wn << 2) | j][lane << 3];
#pragma unroll
    for (int i = 0; i < 4; i++)
#pragma unroll
      for (int j = 0; j < 4; j++)
        acc[i][j] = __builtin_amdgcn_mfma_f32_16x16x32_bf16(a[i], b[j], acc[i][j], 0, 0, 0);
    __syncthreads();
    cur ^= 1;
  }

#pragma unroll
  for (int j = 0; j < 4; j++) {
    const int col = tn + (wn << 6) + (j << 4) + r15;
    const float bs = bias[col];
#pragma unroll
    for (int i = 0; i < 4; i++) {
      const int row0 = tm + (wm << 6) + (i << 4) + ((lane >> 4) << 2);
#pragma unroll
      for (int rr = 0; rr < 4; rr++) {
        const float v = acc[i][j][rr] + bs;
        const size_t off = (size_t)(row0 + rr) * N + col;
        if (BF16OUT)
          ((short*)C)[off] = f2bf(v);
        else
          ((float*)C)[off] = v;
      }
    }
  }
}

// ---------- LayerNorm over last dim (+optional ReLU); writes bf16 (+optional f32) ----------
template <int RELU, int WF32>
__global__ __launch_bounds__(256) void ln_k(const float* __restrict__ in,
                                            const float* __restrict__ ga,
                                            const float* __restrict__ be,
                                            short* __restrict__ ob, float* __restrict__ of,
                                            int N) {
  const int row = blockIdx.x;
  const float* r = in + (size_t)row * N;
  float s = 0.f, s2 = 0.f;
  for (int c = threadIdx.x; c < N; c += 256) {
    float v = r[c];
    s += v;
    s2 += v * v;
  }
  s = waveRed(s);
  s2 = waveRed(s2);
  __shared__ float ps[4], ps2[4];
  const int w = threadIdx.x >> 6;
  if ((threadIdx.x & 63) == 0) { ps[w] = s; ps2[w] = s2; }
  __syncthreads();
  if (threadIdx.x == 0) {
    float a = 0.f, b = 0.f;
    for (int i = 0; i < 4; i++) { a += ps[i]; b += ps2[i]; }
    ps[0] = a; ps2[0] = b;
  }
  __syncthreads();
  const float mean = ps[0] / N;
  float var = ps2[0] / N - mean * mean;
  var = fmaxf(var, 0.f);
  const float rstd = rsqrtf(var + 1e-5f);
  for (int c = threadIdx.x; c < N; c += 256) {
    float v = (r[c] - mean) * rstd * ga[c] + be[c];
    if (RELU) v = fmaxf(v, 0.f);
    ob[(size_t)row * N + c] = f2bf(v);
    if (WF32) of[(size_t)row * N + c] = v;
  }
}

// ---------- weight transpose+convert: src fp32 [K][N] -> dst bf16 [N][K] ----------
struct TT { const float* src; short* dst; int K; int N; };
struct TTab { TT t[12]; int pref[13]; };

__global__ __launch_bounds__(256) void tr_k(TTab tab) {
  const int bid = blockIdx.x;
  int seg = 0;
  while (seg < 11 && bid >= tab.pref[seg + 1]) ++seg;
  const int lt = bid - tab.pref[seg];
  const int K = tab.t[seg].K, N = tab.t[seg].N;
  const int tncnt = N >> 5;
  const int tk = lt / tncnt, tn = lt % tncnt;
  __shared__ float tile[32][33];
  const int x = threadIdx.x & 31, y = threadIdx.x >> 5;  // 32x8
  const float* src = tab.t[seg].src;
  short* dst = tab.t[seg].dst;
#pragma unroll
  for (int i = 0; i < 4; i++) {
    const int kk = (tk << 5) + y + (i << 3);
    tile[y + (i << 3)][x] = src[(size_t)kk * N + (tn << 5) + x];
  }
  __syncthreads();
#pragma unroll
  for (int i = 0; i < 4; i++) {
    const int nn = (tn << 5) + y + (i << 3);
    dst[(size_t)nn * K + (tk << 5) + x] = f2bf(tile[x][y + (i << 3)]);
  }
}

// ---------- x fp32 -> bf16 ----------
__global__ __launch_bounds__(256) void cvt_k(const float* __restrict__ in,
                                             short* __restrict__ outp, int n4) {
  const int i = blockIdx.x * 256 + threadIdx.x;
  if (i < n4) {
    float4 v = ((const float4*)in)[i];
    short4 o;
    o.x = f2bf(v.x); o.y = f2bf(v.y); o.z = f2bf(v.z); o.w = f2bf(v.w);
    ((short4*)outp)[i] = o;
  }
}

// ---------- memory recurrence: 8 persistent WGs, Um slice in static LDS ----------
// mem_t = tanh(xWm_t + mem_{t-1} @ Um + bm(folded into xWm via gemm bias))
// WG wg owns output cols [wg*96, wg*96+96). Inter-WG step barrier: per-WG
// release flags (padded 128B), polled by 8 lanes with acquire loads.
__global__ __launch_bounds__(128) void recur_k(const short* __restrict__ UmT,
                                               const float* __restrict__ xWm,
                                               short* __restrict__ mems, short* ping,
                                               unsigned int* flags) {
  __shared__ short um[144 * 512];   // 147456 B: 144 B-fragments (6 n-tiles x 24 k-frags)
  __shared__ float red[6 * 256];    // 6144 B: cross-wave K-reduce
  const int tid = threadIdx.x, lane = tid & 63, wv = tid >> 6, wg = blockIdx.x;
  const int n0 = wg * 96;

  // One-time load of Um^T slice as MFMA B-fragments.
  for (int f = wv; f < 144; f += 2) {
    const int nt = f / 24, kf = f % 24;
    const int col = n0 + nt * 16 + (lane & 15);
    const int kk = kf * 32 + ((lane >> 4) << 3);
    *(short8v*)(um + ((size_t)f * 64 + lane) * 8) =
        *(const short8v*)(UmT + (size_t)col * 768 + kk);
  }
  __syncthreads();

  for (int t = 0; t < 1024; ++t) {
    const short* mi = ping + (t & 1) * (16 * 768);
    short* mo = ping + ((t & 1) ^ 1) * (16 * 768);

    // prefetch xWm for this step (independent of peers; hides under spin)
    float xw[3][4];
#pragma unroll
    for (int j = 0; j < 3; j++) {
      const int nt = wv * 3 + j;
      const int col = n0 + nt * 16 + (lane & 15);
#pragma unroll
      for (int rr = 0; rr < 4; rr++) {
        const int b = ((lane >> 4) << 2) + rr;
        xw[j][rr] = xWm[((size_t)b * 1024 + t) * 768 + col];
      }
    }

    if (t) {
      if (tid < 8) {
        while (__hip_atomic_load(&flags[tid * 32], __ATOMIC_ACQUIRE,
                                 __HIP_MEMORY_SCOPE_AGENT) < (unsigned)t)
          __builtin_amdgcn_s_sleep(2);
      }
      __syncthreads();
    }

    // A-fragments from mem ping buffer (wave wv covers one K-half)
    short8v Af[12];
#pragma unroll
    for (int i = 0; i < 12; i++) {
      const int kk = (wv * 12 + i) * 32 + ((lane >> 4) << 3);
      Af[i] = *(const short8v*)(mi + (size_t)(lane & 15) * 768 + kk);
    }

    f32x4 acc[6];
#pragma unroll
    for (int n = 0; n < 6; n++) acc[n] = f32x4{0.f, 0.f, 0.f, 0.f};
#pragma unroll
    for (int i = 0; i < 12; i++) {
      const int kf = wv * 12 + i;
#pragma unroll
      for (int n = 0; n < 6; n++) {
        short8v b = *(const short8v*)(um + (((size_t)n * 24 + kf) * 64 + lane) * 8);
        acc[n] = __builtin_amdgcn_mfma_f32_16x16x32_bf16(Af[i], b, acc[n], 0, 0, 0);
      }
    }

// exchange K-halves: wave0 writes nt 3..5, wave1 writes nt 0..2
#define RW(NT)                                                                   \
  {                                                                              \
    _Pragma("unroll") for (int rr = 0; rr < 4; rr++)                             \
        red[(NT)*256 + (lane << 2) + rr] = acc[NT][rr];                          \
  }
    if (wv == 0) { RW(3) RW(4) RW(5) } else { RW(0) RW(1) RW(2) }
    __syncthreads();

#define EPI(J, NT)                                                               \
  {                                                                              \
    const int col = n0 + (NT)*16 + (lane & 15);                                  \
    _Pragma("unroll") for (int rr = 0; rr < 4; rr++) {                           \
      const int b = ((lane >> 4) << 2) + rr;                                     \
      float v = acc[NT][rr] + red[(NT)*256 + (lane << 2) + rr] + xw[J][rr];      \
      v = tanh_fast(v);                                                          \
      const short bf = f2bf(v);                                                  \
      mo[(size_t)b * 768 + col] = bf;                                            \
      mems[((size_t)b * 1024 + t) * 768 + col] = bf;                             \
    }                                                                            \
  }
    if (wv == 0) { EPI(0, 0) EPI(1, 1) EPI(2, 2) } else { EPI(0, 3) EPI(1, 4) EPI(2, 5) }

    __threadfence();  // device-scope: drain stores before publishing
    __syncthreads();
    if (tid == 0)
      __hip_atomic_store(&flags[wg * 32], (unsigned)(t + 1), __ATOMIC_RELEASE,
                         __HIP_MEMORY_SCOPE_AGENT);
  }
#undef RW
#undef EPI
}

// ---------- l2: sum of Frobenius norms ----------
struct PTab { const float* p[37]; int pref[38]; };

__global__ __launch_bounds__(128) void ssq_k(PTab tab, float* ssq) {
  const int bid = blockIdx.x;
  int seg = 0;
  while (seg < 36 && bid >= tab.pref[seg + 1]) ++seg;
  const int off = (bid - tab.pref[seg]) * 128 + threadIdx.x;
  float v = tab.p[seg][off];
  v = waveRed(v * v);
  __shared__ float pp[2];
  if ((threadIdx.x & 63) == 0) pp[threadIdx.x >> 6] = v;
  __syncthreads();
  if (threadIdx.x == 0) atomicAdd(&ssq[seg], pp[0] + pp[1]);
}

__global__ void l2_k(const float* ssq, float* l2) {
  float s = 0.f;
  for (int i = 0; i < 37; i++) s += sqrtf(ssq[i]);
  l2[0] = fminf(fmaxf(s, 0.f), 10.f);
}

// ---------- per-token losses -> scalar ----------
__global__ __launch_bounds__(256) void loss_k(const float* __restrict__ x,
                                              const float* __restrict__ dec,
                                              const float* __restrict__ lat,
                                              const float* __restrict__ l2p,
                                              float* __restrict__ out) {
  const int r = blockIdx.x;
  const int s = r & 1023;
  const float* dr = dec + (size_t)r * 768;
  const float* xr = x + (size_t)r * 768;
  float rs = 0.f;
  for (int c = threadIdx.x; c < 768; c += 256) {
    const float d = dr[c] - xr[c];
    rs += d * d;
  }
  const float* L = lat + (size_t)r * 128;
  const float* Lm = lat + (size_t)(16384 + r) * 128;
  const float* Lp = s ? (L - 128) : (lat + (size_t)32768 * 128);
  float ts = 0.f, dp = 0.f, nl = 0.f, nm = 0.f;
  for (int c = threadIdx.x; c < 128; c += 256) {
    const float a = L[c], m = Lm[c], p = Lp[c];
    const float d = a - p;
    ts += d * d; dp += a * m; nl += a * a; nm += m * m;
  }
  rs = waveRed(rs); ts = waveRed(ts); dp = waveRed(dp); nl = waveRed(nl); nm = waveRed(nm);
  __shared__ float pr[5][4];
  const int w = threadIdx.x >> 6;
  if ((threadIdx.x & 63) == 0) { pr[0][w] = rs; pr[1][w] = ts; pr[2][w] = dp; pr[3][w] = nl; pr[4][w] = nm; }
  __syncthreads();
  if (threadIdx.x == 0) {
    float R = 0, T = 0, Dp = 0, NL = 0, NM = 0;
    for (int i = 0; i < 4; i++) { R += pr[0][i]; T += pr[1][i]; Dp += pr[2][i]; NL += pr[3][i]; NM += pr[4][i]; }
    const float recon = fminf(fmaxf(R / 768.f, 0.f), 10.f);
    const float trans = fminf(fmaxf(T / 128.f, 0.f), 10.f);
    float ctx = 1.f - Dp / (fmaxf(sqrtf(NL), 1e-8f) * fmaxf(sqrtf(NM), 1e-8f));
    ctx = fminf(fmaxf(ctx, 0.f), 10.f);
    float pt = recon + 0.3f * trans + 0.3f * ctx + 1e-4f * l2p[0];
    pt = fminf(fmaxf(pt, 0.f), 100.f);
    atomicAdd(out, pt * 0.0625f);  // /B
  }
}

// ---------- host ----------
extern "C" void kernel_launch(void* const* d_in, const int* in_sizes, int n_in, void* d_out,
                              int out_size, void* d_ws, size_t ws_size, hipStream_t stream) {
  const float* X = (const float*)d_in[0];
  const float* W1 = (const float*)d_in[1];
  const float* b1 = (const float*)d_in[2];
  const float* g1 = (const float*)d_in[3];
  const float* be1 = (const float*)d_in[4];
  const float* Wv = (const float*)d_in[5];
  const float* bv = (const float*)d_in[6];
  const float* Wo = (const float*)d_in[7];
  const float* bo = (const float*)d_in[8];
  const float* W2 = (const float*)d_in[9];
  const float* b2 = (const float*)d_in[10];
  const float* g2 = (const float*)d_in[11];
  const float* be2 = (const float*)d_in[12];
  const float* W3 = (const float*)d_in[13];
  const float* b3 = (const float*)d_in[14];
  const float* g3 = (const float*)d_in[15];
  const float* be3 = (const float*)d_in[16];
  const float* W4 = (const float*)d_in[17];
  const float* b4 = (const float*)d_in[18];
  const float* g4 = (const float*)d_in[19];
  const float* be4 = (const float*)d_in[20];
  const float* W5 = (const float*)d_in[21];
  const float* b5 = (const float*)d_in[22];
  const float* g5 = (const float*)d_in[23];
  const float* be5 = (const float*)d_in[24];
  const float* Wd1 = (const float*)d_in[25];
  const float* bd1 = (const float*)d_in[26];
  const float* gd1 = (const float*)d_in[27];
  const float* bed1 = (const float*)d_in[28];
  const float* Wd2 = (const float*)d_in[29];
  const float* bd2 = (const float*)d_in[30];
  const float* gd2 = (const float*)d_in[31];
  const float* bed2 = (const float*)d_in[32];
  const float* Wd3 = (const float*)d_in[33];
  const float* bd3 = (const float*)d_in[34];
  const float* Wm = (const float*)d_in[35];
  const float* Um = (const float*)d_in[36];
  const float* bm = (const float*)d_in[37];

  char* ws = (char*)d_ws;
  size_t off = 0;
  auto alloc = [&](size_t bytes) -> char* {
    char* p = ws + off;
    off += (bytes + 255) & ~(size_t)255;
    return p;
  };
  const int ME = 32896;  // 2*B*S + 1 (z0) padded to 257*128

  // ---- aliased workspace layout (~209 MB total) ----
  // SH: shared fp32 region; holds (in time order) XWM -> F1/F2 (alternating) -> DEC
  float* SH = (float*)alloc((size_t)ME * 512 * 4);          // 67.4 MB
  short* A0 = (short*)alloc((size_t)ME * 768 * 2);          // 50.5 MB  [x ; mem ; z0 ; pad] bf16
  short* B1 = (short*)alloc((size_t)ME * 512 * 2);          // 33.7 MB  (also Z1, 'e', LATb)
  short* B2 = (short*)alloc((size_t)ME * 512 * 2);          // 33.7 MB
  float* LATf = (float*)alloc((size_t)ME * 128 * 4);        // 16.8 MB  (persists to loss)
  short* W1T = (short*)alloc(512 * 768 * 2);
  short* WvT = (short*)alloc(512 * 512 * 2);
  short* WoT = (short*)alloc(512 * 512 * 2);
  short* W2T = (short*)alloc(512 * 512 * 2);
  short* W3T = (short*)alloc(128 * 512 * 2);
  short* W4T = (short*)alloc(512 * 128 * 2);
  short* W5T = (short*)alloc(128 * 512 * 2);
  short* Wd1T = (short*)alloc(512 * 128 * 2);
  short* Wd2T = (short*)alloc(512 * 512 * 2);
  short* Wd3T = (short*)alloc(768 * 512 * 2);
  short* WmT = (short*)alloc(768 * 768 * 2);
  short* UmT = (short*)alloc(768 * 768 * 2);
  char* MISC = alloc(49152 + 1024 + 512);  // ping(49152) | flags(1024) | ssq | l2
  short* PING = (short*)MISC;
  unsigned int* FLAGS = (unsigned int*)(MISC + 49152);
  float* SSQ = (float*)(MISC + 49152 + 1024);
  float* L2V = (float*)(MISC + 49152 + 1024 + 256);

  float* XWM = SH;  // 16384*768 fp32 (fits in SH)
  float* F1 = SH;   // ME*512 fp32
  float* F2 = SH;   // ME*128 fp32
  float* DEC = SH;  // 16384*768 fp32
  short* Z1 = B1;   // ME*128 bf16 (live range disjoint from 'h'/'a'/'e'/LATb)
  short* LATb = B1; // ME*128 bf16
  (void)ws_size; (void)n_in; (void)out_size;

  // zero: z0 row + pad rows of A0; ping+flags+ssq; out accumulator
  hipMemsetAsync(A0 + (size_t)32768 * 768, 0, (size_t)128 * 768 * 2, stream);
  hipMemsetAsync(MISC, 0, 49152 + 1024 + 512, stream);
  hipMemsetAsync(d_out, 0, sizeof(float), stream);

  // weight transposes (fp32 [K][N] -> bf16 [N][K])
  TTab tt;
  int acc = 0;
  auto addT = [&](int i, const float* s, short* d, int K, int N) {
    tt.t[i] = TT{s, d, K, N};
    tt.pref[i] = acc;
    acc += (K / 32) * (N / 32);
  };
  addT(0, W1, W1T, 768, 512);
  addT(1, Wv, WvT, 512, 512);
  addT(2, Wo, WoT, 512, 512);
  addT(3, W2, W2T, 512, 512);
  addT(4, W3, W3T, 512, 128);
  addT(5, W4, W4T, 128, 512);
  addT(6, W5, W5T, 512, 128);
  addT(7, Wd1, Wd1T, 128, 512);
  addT(8, Wd2, Wd2T, 512, 512);
  addT(9, Wd3, Wd3T, 512, 768);
  addT(10, Wm, WmT, 768, 768);
  addT(11, Um, UmT, 768, 768);
  tt.pref[12] = acc;
  tr_k<<<acc, 256, 0, stream>>>(tt);

  // x -> bf16 rows 0..16383 of A0
  cvt_k<<<(16384 * 768 / 4 + 255) / 256, 256, 0, stream>>>(X, A0, 16384 * 768 / 4);

  // XWM = x @ Wm + bm   (SH)
  gemm_k<0><<<dim3(16384 / 128, 6), 256, 0, stream>>>(A0, WmT, bm, XWM, 16384, 768, 768);

  // recurrence -> fills A0 rows 16384..32767 (mem, bf16); consumes XWM
  recur_k<<<8, 128, 0, stream>>>(UmT, XWM, A0 + (size_t)16384 * 768, PING, FLAGS);

  // ---- encode chain on [x ; mem ; z0 ; pad] (ME rows) ----
  gemm_k<0><<<dim3(ME / 128, 4), 256, 0, stream>>>(A0, W1T, b1, F1, ME, 512, 768);
  ln_k<1, 0><<<ME, 256, 0, stream>>>(F1, g1, be1, B1, nullptr, 512);                 // h -> B1
  gemm_k<1><<<dim3(ME / 128, 4), 256, 0, stream>>>(B1, WvT, bv, B2, ME, 512, 512);   // v -> B2
  gemm_k<1><<<dim3(ME / 128, 4), 256, 0, stream>>>(B2, WoT, bo, B1, ME, 512, 512);   // a -> B1
  gemm_k<0><<<dim3(ME / 128, 4), 256, 0, stream>>>(B1, W2T, b2, F1, ME, 512, 512);
  ln_k<1, 0><<<ME, 256, 0, stream>>>(F1, g2, be2, B2, nullptr, 512);                 // g -> B2
  gemm_k<0><<<dim3(ME / 128, 1), 256, 0, stream>>>(B2, W3T, b3, F2, ME, 128, 512);
  ln_k<0, 0><<<ME, 256, 0, stream>>>(F2, g3, be3, Z1, nullptr, 128);                 // zl -> Z1(B1)
  gemm_k<0><<<dim3(ME / 128, 4), 256, 0, stream>>>(Z1, W4T, b4, F1, ME, 512, 128);
  ln_k<1, 0><<<ME, 256, 0, stream>>>(F1, g4, be4, B1, nullptr, 512);                 // e -> B1
  gemm_k<0><<<dim3(ME / 128, 1), 256, 0, stream>>>(B1, W5T, b5, F2, ME, 128, 512);
  ln_k<0, 1><<<ME, 256, 0, stream>>>(F2, g5, be5, LATb, LATf, 128);                  // lat

  // ---- decode chain on lat rows 0..16383 ----
  gemm_k<0><<<dim3(16384 / 128, 4), 256, 0, stream>>>(LATb, Wd1T, bd1, F1, 16384, 512, 128);
  ln_k<1, 0><<<16384, 256, 0, stream>>>(F1, gd1, bed1, B2, nullptr, 512);
  gemm_k<0><<<dim3(16384 / 128, 4), 256, 0, stream>>>(B2, Wd2T, bd2, F1, 16384, 512, 512);
  ln_k<1, 0><<<16384, 256, 0, stream>>>(F1, gd2, bed2, B1, nullptr, 512);
  gemm_k<0><<<dim3(16384 / 128, 6), 256, 0, stream>>>(B1, Wd3T, bd3, DEC, 16384, 768, 512);

  // ---- l2 ----
  PTab pt;
  int blk = 0;
  for (int i = 0; i < 37; i++) {
    pt.p[i] = (const float*)d_in[i + 1];
    pt.pref[i] = blk;
    blk += in_sizes[i + 1] / 128;
  }
  pt.pref[37] = blk;
  ssq_k<<<blk, 128, 0, stream>>>(pt, SSQ);
  l2_k<<<1, 1, 0, stream>>>(SSQ, L2V);

  // ---- losses -> scalar ----
  loss_k<<<16384, 256, 0, stream>>>(X, DEC, LATf, L2V, (float*)d_out);
}

// Round 3
// 5957.452 us; speedup vs baseline: 1.1407x; 1.1407x over previous
//
#include <hip/hip_runtime.h>

#define DI __device__ __forceinline__

typedef __attribute__((ext_vector_type(8))) short short8v;
typedef __attribute__((ext_vector_type(4))) float f32x4;
typedef unsigned long long u64;

// ---------- small helpers ----------
DI short f2bf(float f) {
  unsigned u = __float_as_uint(f);
  u += 0x7fffu + ((u >> 16) & 1u);  // RNE
  return (short)(u >> 16);
}

DI float waveRed(float v) {
#pragma unroll
  for (int m = 32; m; m >>= 1) v += __shfl_xor(v, m, 64);
  return v;
}

DI float tanh_fast(float x) {
  float ax = fabsf(x);
  float e = __expf(2.f * ax);
  float t = 1.f - 2.f / (e + 1.f);
  return copysignf(t, x);
}

DI void gl16(const void* g, void* l) {
  // 16B-wide async global->LDS; LDS dest = wave-uniform base + lane*16
  __builtin_amdgcn_global_load_lds((const __attribute__((address_space(1))) void*)g,
                                   (__attribute__((address_space(3))) void*)l, 16, 0, 0);
}

// ---------- GEMM: C[M,N] = A[M,K](bf16) * B (BT[N,K] bf16) + bias ----------
// 128x128 tile, BK=32, 256 threads (4 waves as 2x2), mfma 16x16x32 bf16.
template <int BF16OUT>
__global__ __launch_bounds__(256) void gemm_k(const short* __restrict__ A,
                                              const short* __restrict__ BT,
                                              const float* __restrict__ bias,
                                              void* __restrict__ C, int M, int N, int K) {
  __shared__ short sA[2][8][512];  // [dbuf][m-subtile][lane*8] fragment-linear
  __shared__ short sB[2][8][512];
  const int tid = threadIdx.x, lane = tid & 63, wid = tid >> 6;
  const int tm = blockIdx.x << 7, tn = blockIdx.y << 7;
  const int wm = wid >> 1, wn = wid & 1;
  const int r15 = lane & 15, kq = (lane >> 4) << 3;
  const int KT = K >> 5;

  f32x4 acc[4][4];
#pragma unroll
  for (int i = 0; i < 4; i++)
#pragma unroll
    for (int j = 0; j < 4; j++) acc[i][j] = f32x4{0.f, 0.f, 0.f, 0.f};

  auto stage = [&](int kt, int buf) {
    const int k0 = kt << 5;
#pragma unroll
    for (int i = 0; i < 2; i++) {
      const int st = (wid << 1) | i;
      gl16(A + (size_t)(tm + (st << 4) + r15) * K + k0 + kq, &sA[buf][st][0]);
      gl16(BT + (size_t)(tn + (st << 4) + r15) * K + k0 + kq, &sB[buf][st][0]);
    }
  };

  stage(0, 0);
  __syncthreads();
  int cur = 0;
  for (int kt = 0; kt < KT; ++kt) {
    if (kt + 1 < KT) stage(kt + 1, cur ^ 1);
    short8v a[4], b[4];
#pragma unroll
    for (int i = 0; i < 4; i++) a[i] = *(const short8v*)&sA[cur][(wm << 2) | i][lane << 3];
#pragma unroll
    for (int j = 0; j < 4; j++) b[j] = *(const short8v*)&sB[cur][(wn << 2) | j][lane << 3];
#pragma unroll
    for (int i = 0; i < 4; i++)
#pragma unroll
      for (int j = 0; j < 4; j++)
        acc[i][j] = __builtin_amdgcn_mfma_f32_16x16x32_bf16(a[i], b[j], acc[i][j], 0, 0, 0);
    __syncthreads();
    cur ^= 1;
  }

#pragma unroll
  for (int j = 0; j < 4; j++) {
    const int col = tn + (wn << 6) + (j << 4) + r15;
    const float bs = bias[col];
#pragma unroll
    for (int i = 0; i < 4; i++) {
      const int row0 = tm + (wm << 6) + (i << 4) + ((lane >> 4) << 2);
#pragma unroll
      for (int rr = 0; rr < 4; rr++) {
        const float v = acc[i][j][rr] + bs;
        const size_t off = (size_t)(row0 + rr) * N + col;
        if (BF16OUT)
          ((short*)C)[off] = f2bf(v);
        else
          ((float*)C)[off] = v;
      }
    }
  }
}

// ---------- LayerNorm over last dim (+optional ReLU); writes bf16 (+optional f32) ----------
template <int RELU, int WF32>
__global__ __launch_bounds__(256) void ln_k(const float* __restrict__ in,
                                            const float* __restrict__ ga,
                                            const float* __restrict__ be,
                                            short* __restrict__ ob, float* __restrict__ of,
                                            int N) {
  const int row = blockIdx.x;
  const float* r = in + (size_t)row * N;
  float s = 0.f, s2 = 0.f;
  for (int c = threadIdx.x; c < N; c += 256) {
    float v = r[c];
    s += v;
    s2 += v * v;
  }
  s = waveRed(s);
  s2 = waveRed(s2);
  __shared__ float ps[4], ps2[4];
  const int w = threadIdx.x >> 6;
  if ((threadIdx.x & 63) == 0) { ps[w] = s; ps2[w] = s2; }
  __syncthreads();
  if (threadIdx.x == 0) {
    float a = 0.f, b = 0.f;
    for (int i = 0; i < 4; i++) { a += ps[i]; b += ps2[i]; }
    ps[0] = a; ps2[0] = b;
  }
  __syncthreads();
  const float mean = ps[0] / N;
  float var = ps2[0] / N - mean * mean;
  var = fmaxf(var, 0.f);
  const float rstd = rsqrtf(var + 1e-5f);
  for (int c = threadIdx.x; c < N; c += 256) {
    float v = (r[c] - mean) * rstd * ga[c] + be[c];
    if (RELU) v = fmaxf(v, 0.f);
    ob[(size_t)row * N + c] = f2bf(v);
    if (WF32) of[(size_t)row * N + c] = v;
  }
}

// ---------- weight transpose+convert: src fp32 [K][N] -> dst bf16 [N][K] ----------
struct TT { const float* src; short* dst; int K; int N; };
struct TTab { TT t[12]; int pref[13]; };

__global__ __launch_bounds__(256) void tr_k(TTab tab) {
  const int bid = blockIdx.x;
  int seg = 0;
  while (seg < 11 && bid >= tab.pref[seg + 1]) ++seg;
  const int lt = bid - tab.pref[seg];
  const int K = tab.t[seg].K, N = tab.t[seg].N;
  const int tncnt = N >> 5;
  const int tk = lt / tncnt, tn = lt % tncnt;
  __shared__ float tile[32][33];
  const int x = threadIdx.x & 31, y = threadIdx.x >> 5;  // 32x8
  const float* src = tab.t[seg].src;
  short* dst = tab.t[seg].dst;
#pragma unroll
  for (int i = 0; i < 4; i++) {
    const int kk = (tk << 5) + y + (i << 3);
    tile[y + (i << 3)][x] = src[(size_t)kk * N + (tn << 5) + x];
  }
  __syncthreads();
#pragma unroll
  for (int i = 0; i < 4; i++) {
    const int nn = (tn << 5) + y + (i << 3);
    dst[(size_t)nn * K + (tk << 5) + x] = f2bf(tile[x][y + (i << 3)]);
  }
}

// ---------- x fp32 -> bf16 ----------
__global__ __launch_bounds__(256) void cvt_k(const float* __restrict__ in,
                                             short* __restrict__ outp, int n4) {
  const int i = blockIdx.x * 256 + threadIdx.x;
  if (i < n4) {
    float4 v = ((const float4*)in)[i];
    short4 o;
    o.x = f2bf(v.x); o.y = f2bf(v.y); o.z = f2bf(v.z); o.w = f2bf(v.w);
    ((short4*)outp)[i] = o;
  }
}

// ---------- memory recurrence: 8 persistent WGs, Um slice in static LDS ----------
// mem_t = tanh(xWm_t + mem_{t-1} @ Um).  WG wg owns output cols [wg*96, wg*96+96).
// Cross-WG exchange via CACHE-BYPASSING relaxed agent atomics (sc0/sc1 write-through
// to the Infinity-Cache coherence point) — no buffer_wbl2/buffer_inv per step.
// Ordering: data stores -> s_waitcnt vmcnt(0) (per wave) -> __syncthreads -> flag store.
__global__ __launch_bounds__(128) void recur_k(const short* __restrict__ UmT,
                                               const float* __restrict__ xWm,
                                               short* __restrict__ mems, short* ping,
                                               unsigned int* flags) {
  __shared__ short um[144 * 512];   // 147456 B: 144 B-fragments (6 n-tiles x 24 k-frags)
  __shared__ float red[6 * 256];    // 6144 B: cross-wave K-reduce
  const int tid = threadIdx.x, lane = tid & 63, wv = tid >> 6, wg = blockIdx.x;
  const int n0 = wg * 96;

  // One-time load of Um^T slice as MFMA B-fragments.
  for (int f = wv; f < 144; f += 2) {
    const int nt = f / 24, kf = f % 24;
    const int col = n0 + nt * 16 + (lane & 15);
    const int kk = kf * 32 + ((lane >> 4) << 3);
    *(short8v*)(um + ((size_t)f * 64 + lane) * 8) =
        *(const short8v*)(UmT + (size_t)col * 768 + kk);
  }
  __syncthreads();

  for (int t = 0; t < 1024; ++t) {
    const u64* mi64 = (const u64*)(ping + (t & 1) * (16 * 768));
    short* mo = ping + ((t & 1) ^ 1) * (16 * 768);

    // prefetch xWm for this step (plain cached loads; read-only data)
    float xw[3][4];
#pragma unroll
    for (int j = 0; j < 3; j++) {
      const int nt = wv * 3 + j;
      const int col = n0 + nt * 16 + (lane & 15);
#pragma unroll
      for (int rr = 0; rr < 4; rr++) {
        const int b = ((lane >> 4) << 2) + rr;
        xw[j][rr] = xWm[((size_t)b * 1024 + t) * 768 + col];
      }
    }

    if (t) {
      if (tid < 8) {
        while (__hip_atomic_load(&flags[tid * 32], __ATOMIC_RELAXED,
                                 __HIP_MEMORY_SCOPE_AGENT) < (unsigned)t)
          __builtin_amdgcn_s_sleep(1);
      }
      __syncthreads();
    }

    // A-fragments via cache-bypassing u64 atomic loads (always fresh at IC)
    short8v Af[12];
#pragma unroll
    for (int i = 0; i < 12; i++) {
      const int kk = (wv * 12 + i) * 32 + ((lane >> 4) << 3);
      const size_t base = ((size_t)(lane & 15) * 768 + kk) >> 2;  // u64 index
      union { u64 q[2]; short8v s; } u;
      u.q[0] = __hip_atomic_load(mi64 + base, __ATOMIC_RELAXED, __HIP_MEMORY_SCOPE_AGENT);
      u.q[1] = __hip_atomic_load(mi64 + base + 1, __ATOMIC_RELAXED, __HIP_MEMORY_SCOPE_AGENT);
      Af[i] = u.s;
    }

    f32x4 acc[6];
#pragma unroll
    for (int n = 0; n < 6; n++) acc[n] = f32x4{0.f, 0.f, 0.f, 0.f};
#pragma unroll
    for (int i = 0; i < 12; i++) {
      const int kf = wv * 12 + i;
#pragma unroll
      for (int n = 0; n < 6; n++) {
        short8v b = *(const short8v*)(um + (((size_t)n * 24 + kf) * 64 + lane) * 8);
        acc[n] = __builtin_amdgcn_mfma_f32_16x16x32_bf16(Af[i], b, acc[n], 0, 0, 0);
      }
    }

// exchange K-halves: wave0 writes nt 3..5, wave1 writes nt 0..2
#define RW(NT)                                                                   \
  {                                                                              \
    _Pragma("unroll") for (int rr = 0; rr < 4; rr++)                             \
        red[(NT)*256 + (lane << 2) + rr] = acc[NT][rr];                          \
  }
    if (wv == 0) { RW(3) RW(4) RW(5) } else { RW(0) RW(1) RW(2) }
    __syncthreads();

// epilogue: tanh -> bf16; archive to mems (cached); publish to mo via packed
// u32 relaxed agent atomics (even lane packs its col c and neighbor's c+1).
#define EPI(J, NT)                                                               \
  {                                                                              \
    const int col = n0 + (NT)*16 + (lane & 15);                                  \
    _Pragma("unroll") for (int rr = 0; rr < 4; rr++) {                           \
      const int b = ((lane >> 4) << 2) + rr;                                     \
      float v = acc[NT][rr] + red[(NT)*256 + (lane << 2) + rr] + xw[J][rr];      \
      v = tanh_fast(v);                                                          \
      const short bf = f2bf(v);                                                  \
      mems[((size_t)b * 1024 + t) * 768 + col] = bf;                             \
      const int nb = __shfl_xor((int)(unsigned short)bf, 1, 64);                 \
      if (!(lane & 1)) {                                                         \
        const unsigned pk = (unsigned)(unsigned short)bf | ((unsigned)nb << 16); \
        __hip_atomic_store((unsigned*)(mo + (size_t)b * 768 + col), pk,          \
                           __ATOMIC_RELAXED, __HIP_MEMORY_SCOPE_AGENT);          \
      }                                                                          \
    }                                                                            \
  }
    if (wv == 0) { EPI(0, 0) EPI(1, 1) EPI(2, 2) } else { EPI(0, 3) EPI(1, 4) EPI(2, 5) }

    asm volatile("s_waitcnt vmcnt(0)" ::: "memory");  // per-wave drain to coherence point
    __syncthreads();                                  // both waves drained
    if (tid == 0)
      __hip_atomic_store(&flags[wg * 32], (unsigned)(t + 1), __ATOMIC_RELAXED,
                         __HIP_MEMORY_SCOPE_AGENT);
  }
#undef RW
#undef EPI
}

// ---------- l2: sum of Frobenius norms ----------
struct PTab { const float* p[37]; int pref[38]; };

__global__ __launch_bounds__(128) void ssq_k(PTab tab, float* ssq) {
  const int bid = blockIdx.x;
  int seg = 0;
  while (seg < 36 && bid >= tab.pref[seg + 1]) ++seg;
  const int off = (bid - tab.pref[seg]) * 128 + threadIdx.x;
  float v = tab.p[seg][off];
  v = waveRed(v * v);
  __shared__ float pp[2];
  if ((threadIdx.x & 63) == 0) pp[threadIdx.x >> 6] = v;
  __syncthreads();
  if (threadIdx.x == 0) atomicAdd(&ssq[seg], pp[0] + pp[1]);
}

__global__ void l2_k(const float* ssq, float* l2) {
  float s = 0.f;
  for (int i = 0; i < 37; i++) s += sqrtf(ssq[i]);
  l2[0] = fminf(fmaxf(s, 0.f), 10.f);
}

// ---------- per-token losses -> scalar ----------
__global__ __launch_bounds__(256) void loss_k(const float* __restrict__ x,
                                              const float* __restrict__ dec,
                                              const float* __restrict__ lat,
                                              const float* __restrict__ l2p,
                                              float* __restrict__ out) {
  const int r = blockIdx.x;
  const int s = r & 1023;
  const float* dr = dec + (size_t)r * 768;
  const float* xr = x + (size_t)r * 768;
  float rs = 0.f;
  for (int c = threadIdx.x; c < 768; c += 256) {
    const float d = dr[c] - xr[c];
    rs += d * d;
  }
  const float* L = lat + (size_t)r * 128;
  const float* Lm = lat + (size_t)(16384 + r) * 128;
  const float* Lp = s ? (L - 128) : (lat + (size_t)32768 * 128);
  float ts = 0.f, dp = 0.f, nl = 0.f, nm = 0.f;
  for (int c = threadIdx.x; c < 128; c += 256) {
    const float a = L[c], m = Lm[c], p = Lp[c];
    const float d = a - p;
    ts += d * d; dp += a * m; nl += a * a; nm += m * m;
  }
  rs = waveRed(rs); ts = waveRed(ts); dp = waveRed(dp); nl = waveRed(nl); nm = waveRed(nm);
  __shared__ float pr[5][4];
  const int w = threadIdx.x >> 6;
  if ((threadIdx.x & 63) == 0) { pr[0][w] = rs; pr[1][w] = ts; pr[2][w] = dp; pr[3][w] = nl; pr[4][w] = nm; }
  __syncthreads();
  if (threadIdx.x == 0) {
    float R = 0, T = 0, Dp = 0, NL = 0, NM = 0;
    for (int i = 0; i < 4; i++) { R += pr[0][i]; T += pr[1][i]; Dp += pr[2][i]; NL += pr[3][i]; NM += pr[4][i]; }
    const float recon = fminf(fmaxf(R / 768.f, 0.f), 10.f);
    const float trans = fminf(fmaxf(T / 128.f, 0.f), 10.f);
    float ctx = 1.f - Dp / (fmaxf(sqrtf(NL), 1e-8f) * fmaxf(sqrtf(NM), 1e-8f));
    ctx = fminf(fmaxf(ctx, 0.f), 10.f);
    float pt = recon + 0.3f * trans + 0.3f * ctx + 1e-4f * l2p[0];
    pt = fminf(fmaxf(pt, 0.f), 100.f);
    atomicAdd(out, pt * 0.0625f);  // /B
  }
}

// ---------- host ----------
extern "C" void kernel_launch(void* const* d_in, const int* in_sizes, int n_in, void* d_out,
                              int out_size, void* d_ws, size_t ws_size, hipStream_t stream) {
  const float* X = (const float*)d_in[0];
  const float* W1 = (const float*)d_in[1];
  const float* b1 = (const float*)d_in[2];
  const float* g1 = (const float*)d_in[3];
  const float* be1 = (const float*)d_in[4];
  const float* Wv = (const float*)d_in[5];
  const float* bv = (const float*)d_in[6];
  const float* Wo = (const float*)d_in[7];
  const float* bo = (const float*)d_in[8];
  const float* W2 = (const float*)d_in[9];
  const float* b2 = (const float*)d_in[10];
  const float* g2 = (const float*)d_in[11];
  const float* be2 = (const float*)d_in[12];
  const float* W3 = (const float*)d_in[13];
  const float* b3 = (const float*)d_in[14];
  const float* g3 = (const float*)d_in[15];
  const float* be3 = (const float*)d_in[16];
  const float* W4 = (const float*)d_in[17];
  const float* b4 = (const float*)d_in[18];
  const float* g4 = (const float*)d_in[19];
  const float* be4 = (const float*)d_in[20];
  const float* W5 = (const float*)d_in[21];
  const float* b5 = (const float*)d_in[22];
  const float* g5 = (const float*)d_in[23];
  const float* be5 = (const float*)d_in[24];
  const float* Wd1 = (const float*)d_in[25];
  const float* bd1 = (const float*)d_in[26];
  const float* gd1 = (const float*)d_in[27];
  const float* bed1 = (const float*)d_in[28];
  const float* Wd2 = (const float*)d_in[29];
  const float* bd2 = (const float*)d_in[30];
  const float* gd2 = (const float*)d_in[31];
  const float* bed2 = (const float*)d_in[32];
  const float* Wd3 = (const float*)d_in[33];
  const float* bd3 = (const float*)d_in[34];
  const float* Wm = (const float*)d_in[35];
  const float* Um = (const float*)d_in[36];
  const float* bm = (const float*)d_in[37];

  char* ws = (char*)d_ws;
  size_t off = 0;
  auto alloc = [&](size_t bytes) -> char* {
    char* p = ws + off;
    off += (bytes + 255) & ~(size_t)255;
    return p;
  };
  const int ME = 32896;  // 2*B*S + 1 (z0) padded to 257*128

  // ---- aliased workspace layout (~209 MB total) ----
  // SH: shared fp32 region; holds (in time order) XWM -> F1/F2 (alternating) -> DEC
  float* SH = (float*)alloc((size_t)ME * 512 * 4);          // 67.4 MB
  short* A0 = (short*)alloc((size_t)ME * 768 * 2);          // 50.5 MB  [x ; mem ; z0 ; pad] bf16
  short* B1 = (short*)alloc((size_t)ME * 512 * 2);          // 33.7 MB  (also Z1, 'e', LATb)
  short* B2 = (short*)alloc((size_t)ME * 512 * 2);          // 33.7 MB
  float* LATf = (float*)alloc((size_t)ME * 128 * 4);        // 16.8 MB  (persists to loss)
  short* W1T = (short*)alloc(512 * 768 * 2);
  short* WvT = (short*)alloc(512 * 512 * 2);
  short* WoT = (short*)alloc(512 * 512 * 2);
  short* W2T = (short*)alloc(512 * 512 * 2);
  short* W3T = (short*)alloc(128 * 512 * 2);
  short* W4T = (short*)alloc(512 * 128 * 2);
  short* W5T = (short*)alloc(128 * 512 * 2);
  short* Wd1T = (short*)alloc(512 * 128 * 2);
  short* Wd2T = (short*)alloc(512 * 512 * 2);
  short* Wd3T = (short*)alloc(768 * 512 * 2);
  short* WmT = (short*)alloc(768 * 768 * 2);
  short* UmT = (short*)alloc(768 * 768 * 2);
  char* MISC = alloc(49152 + 1024 + 512);  // ping(49152) | flags(1024) | ssq | l2
  short* PING = (short*)MISC;
  unsigned int* FLAGS = (unsigned int*)(MISC + 49152);
  float* SSQ = (float*)(MISC + 49152 + 1024);
  float* L2V = (float*)(MISC + 49152 + 1024 + 256);

  float* XWM = SH;  // 16384*768 fp32 (fits in SH)
  float* F1 = SH;   // ME*512 fp32
  float* F2 = SH;   // ME*128 fp32
  float* DEC = SH;  // 16384*768 fp32
  short* Z1 = B1;   // ME*128 bf16 (live range disjoint from 'h'/'a'/'e'/LATb)
  short* LATb = B1; // ME*128 bf16
  (void)ws_size; (void)n_in; (void)out_size;

  // zero: z0 row + pad rows of A0; ping+flags+ssq; out accumulator
  hipMemsetAsync(A0 + (size_t)32768 * 768, 0, (size_t)128 * 768 * 2, stream);
  hipMemsetAsync(MISC, 0, 49152 + 1024 + 512, stream);
  hipMemsetAsync(d_out, 0, sizeof(float), stream);

  // weight transposes (fp32 [K][N] -> bf16 [N][K])
  TTab tt;
  int acc = 0;
  auto addT = [&](int i, const float* s, short* d, int K, int N) {
    tt.t[i] = TT{s, d, K, N};
    tt.pref[i] = acc;
    acc += (K / 32) * (N / 32);
  };
  addT(0, W1, W1T, 768, 512);
  addT(1, Wv, WvT, 512, 512);
  addT(2, Wo, WoT, 512, 512);
  addT(3, W2, W2T, 512, 512);
  addT(4, W3, W3T, 512, 128);
  addT(5, W4, W4T, 128, 512);
  addT(6, W5, W5T, 512, 128);
  addT(7, Wd1, Wd1T, 128, 512);
  addT(8, Wd2, Wd2T, 512, 512);
  addT(9, Wd3, Wd3T, 512, 768);
  addT(10, Wm, WmT, 768, 768);
  addT(11, Um, UmT, 768, 768);
  tt.pref[12] = acc;
  tr_k<<<acc, 256, 0, stream>>>(tt);

  // x -> bf16 rows 0..16383 of A0
  cvt_k<<<(16384 * 768 / 4 + 255) / 256, 256, 0, stream>>>(X, A0, 16384 * 768 / 4);

  // XWM = x @ Wm + bm   (SH)
  gemm_k<0><<<dim3(16384 / 128, 6), 256, 0, stream>>>(A0, WmT, bm, XWM, 16384, 768, 768);

  // recurrence -> fills A0 rows 16384..32767 (mem, bf16); consumes XWM
  recur_k<<<8, 128, 0, stream>>>(UmT, XWM, A0 + (size_t)16384 * 768, PING, FLAGS);

  // ---- encode chain on [x ; mem ; z0 ; pad] (ME rows) ----
  gemm_k<0><<<dim3(ME / 128, 4), 256, 0, stream>>>(A0, W1T, b1, F1, ME, 512, 768);
  ln_k<1, 0><<<ME, 256, 0, stream>>>(F1, g1, be1, B1, nullptr, 512);                 // h -> B1
  gemm_k<1><<<dim3(ME / 128, 4), 256, 0, stream>>>(B1, WvT, bv, B2, ME, 512, 512);   // v -> B2
  gemm_k<1><<<dim3(ME / 128, 4), 256, 0, stream>>>(B2, WoT, bo, B1, ME, 512, 512);   // a -> B1
  gemm_k<0><<<dim3(ME / 128, 4), 256, 0, stream>>>(B1, W2T, b2, F1, ME, 512, 512);
  ln_k<1, 0><<<ME, 256, 0, stream>>>(F1, g2, be2, B2, nullptr, 512);                 // g -> B2
  gemm_k<0><<<dim3(ME / 128, 1), 256, 0, stream>>>(B2, W3T, b3, F2, ME, 128, 512);
  ln_k<0, 0><<<ME, 256, 0, stream>>>(F2, g3, be3, Z1, nullptr, 128);                 // zl -> Z1(B1)
  gemm_k<0><<<dim3(ME / 128, 4), 256, 0, stream>>>(Z1, W4T, b4, F1, ME, 512, 128);
  ln_k<1, 0><<<ME, 256, 0, stream>>>(F1, g4, be4, B1, nullptr, 512);                 // e -> B1
  gemm_k<0><<<dim3(ME / 128, 1), 256, 0, stream>>>(B1, W5T, b5, F2, ME, 128, 512);
  ln_k<0, 1><<<ME, 256, 0, stream>>>(F2, g5, be5, LATb, LATf, 128);                  // lat

  // ---- decode chain on lat rows 0..16383 ----
  gemm_k<0><<<dim3(16384 / 128, 4), 256, 0, stream>>>(LATb, Wd1T, bd1, F1, 16384, 512, 128);
  ln_k<1, 0><<<16384, 256, 0, stream>>>(F1, gd1, bed1, B2, nullptr, 512);
  gemm_k<0><<<dim3(16384 / 128, 4), 256, 0, stream>>>(B2, Wd2T, bd2, F1, 16384, 512, 512);
  ln_k<1, 0><<<16384, 256, 0, stream>>>(F1, gd2, bed2, B1, nullptr, 512);
  gemm_k<0><<<dim3(16384 / 128, 6), 256, 0, stream>>>(B1, Wd3T, bd3, DEC, 16384, 768, 512);

  // ---- l2 ----
  PTab pt;
  int blk = 0;
  for (int i = 0; i < 37; i++) {
    pt.p[i] = (const float*)d_in[i + 1];
    pt.pref[i] = blk;
    blk += in_sizes[i + 1] / 128;
  }
  pt.pref[37] = blk;
  ssq_k<<<blk, 128, 0, stream>>>(pt, SSQ);
  l2_k<<<1, 1, 0, stream>>>(SSQ, L2V);

  // ---- losses -> scalar ----
  loss_k<<<16384, 256, 0, stream>>>(X, DEC, LATf, L2V, (float*)d_out);
}